// Round 7
// baseline (118.836 us; speedup 1.0000x reference)
//
#include <hip/hip_runtime.h>

// Problem constants
#define CIN   16
#define COUT  32
#define BATCH 2
#define DSP   32
#define HSP   128
#define WSP   128
#define NVOX  (BATCH*DSP*HSP*WSP)   // 1,048,576 voxels (unpadded, for dedup map)

// padded dense grid (1-voxel zero halo)
#define DP (DSP+2)     // 34
#define HP (HSP+2)     // 130
#define WP (WSP+2)     // 130
#define ZSTR (HP*WP)   // 16900
#define NVOXP (BATCH*DP*HP*WP)      // 1,149,200

// conv tile: 4(z) x 4(y) x 32(x)
#define TZ 4
#define TY 4
#define TX 32
#define NTILES 2048
#define NPAIR 14            // 27 taps -> 14 K=32 pairs (last padded with zero weights)
#define NWREP ((NPAIR*2*64*8 + 255)/256)   // 56 repack blocks

typedef __bf16 bf16x8 __attribute__((ext_vector_type(8)));
typedef float  f32x4  __attribute__((ext_vector_type(4)));

// ---- fused: dedup (last-write-wins via atomicMax) + weight repack ----
// wpack flat idx = ((pair*2 + half)*64 + lane)*8 + j
// tap = 2*pair + ((lane>>4)>>1), ci = ((lane>>4)&1)*8 + j, cout = half*16 + (lane&15)
__global__ void k_prep(const int4* __restrict__ coords, int n, int nbDedup,
                       int* __restrict__ map,
                       const float* __restrict__ w, __bf16* __restrict__ wpack) {
    int bb = blockIdx.x;
    if (bb < nbDedup) {
        int p = bb * 256 + threadIdx.x;
        if (p >= n) return;
        int4 c = coords[p];
        int vox = ((c.x*DSP + c.y)*HSP + c.z)*WSP + c.w;
        atomicMax(&map[vox], p);
    } else {
        int i = (bb - nbDedup) * 256 + threadIdx.x;   // 14336 total
        if (i >= NPAIR*2*64*8) return;
        int j = i & 7, l = (i>>3) & 63, h = (i>>9) & 1, p = i >> 10;
        int tap = 2*p + ((l>>4)>>1);
        int co  = h*16 + (l & 15);
        int ci  = ((l>>4)&1)*8 + j;
        float v = (tap < 27) ? w[(co*CIN + ci)*27 + tap] : 0.0f;
        wpack[i] = (__bf16)v;
    }
}

// ---- winners write their bf16 feature vector into the PADDED dense grid ----
__global__ void k_scatter(const int4* __restrict__ coords, const int* __restrict__ map,
                          const float* __restrict__ feat, __bf16* __restrict__ dense,
                          int n) {
    int p = blockIdx.x * 256 + threadIdx.x;
    if (p >= n) return;
    int4 c = coords[p];
    int vox = ((c.x*DSP + c.y)*HSP + c.z)*WSP + c.w;
    if (map[vox] != p) return;                        // only last-writer survives
    const float4* fp = (const float4*)(feat + (size_t)p*CIN);
    float4 f0 = fp[0], f1 = fp[1], f2 = fp[2], f3 = fp[3];
    bf16x8 lo = { (__bf16)f0.x,(__bf16)f0.y,(__bf16)f0.z,(__bf16)f0.w,
                  (__bf16)f1.x,(__bf16)f1.y,(__bf16)f1.z,(__bf16)f1.w };
    bf16x8 hi = { (__bf16)f2.x,(__bf16)f2.y,(__bf16)f2.z,(__bf16)f2.w,
                  (__bf16)f3.x,(__bf16)f3.y,(__bf16)f3.z,(__bf16)f3.w };
    size_t voxp = (((size_t)c.x*DP + (c.y+1))*HP + (c.z+1))*WP + (c.w+1);
    __bf16* d = dense + voxp*CIN;
    *(bf16x8*)d       = lo;
    *(bf16x8*)(d + 8) = hi;
}

// ------- dense conv (MFMA), LDS-free, barrier-free, padded-grid A reads -------
__global__ __launch_bounds__(256, 4) void k_conv(
    const __bf16* __restrict__ dense, const __bf16* __restrict__ wpack,
    const float* __restrict__ bias, float* __restrict__ out)
{
    // XCD-aware bijective swizzle: 2048 % 8 == 0
    int bid  = blockIdx.x;
    int tile = (bid & 7) * (NTILES/8) + (bid >> 3);
    int txi = tile & 3;
    int tyi = (tile >> 2) & 31;
    int tzi = (tile >> 7) & 7;
    int b   = tile >> 10;
    int z0 = tzi*TZ, y0 = tyi*TY, x0 = txi*TX;

    int tid  = threadIdx.x;
    int lane = tid & 63, wave = tid >> 6;
    int lx16  = lane & 15;
    int lhalf = (lane >> 4) & 1;
    int ltp   = (lane >> 4) >> 1;

    // per-lane padded-voxel offset per tap-pair (relative to center voxel)
    int woff[NPAIR];
    #pragma unroll
    for (int p = 0; p < NPAIR; ++p) {
        int tap = 2*p + ltp; if (tap > 26) tap = 26;   // A in-bounds; B zero there
        int kd = tap/9, kh = (tap/3)%3, kw = tap%3;
        woff[p] = (kd-1)*ZSTR + (kh-1)*WP + (kw-1);
    }
    float bv0 = bias[lx16], bv1 = bias[16 + lx16];

    // lane's center-voxel base (padded coords); +1 halo shift built in
    size_t vbase = (((size_t)b*DP + (z0 + wave + 1))*HP + (y0 + 1))*WP + (x0 + lx16 + 1);
    const __bf16* pb = dense + vbase*CIN + lhalf*8;

    f32x4 acc[8][2];
    #pragma unroll
    for (int gi = 0; gi < 8; ++gi) {
        acc[gi][0] = (f32x4){0.f,0.f,0.f,0.f};
        acc[gi][1] = (f32x4){0.f,0.f,0.f,0.f};
    }

    // gi -> y = gi>>1, xg = gi&1 : voxel offset y*WP + xg*16
    bf16x8 w0 = *(const bf16x8*)(wpack + (size_t)(0*64 + lane)*8);
    bf16x8 w1 = *(const bf16x8*)(wpack + (size_t)(1*64 + lane)*8);
    #pragma unroll 2
    for (int p = 0; p < NPAIR; ++p) {
        int pn = (p + 1 < NPAIR) ? p + 1 : 0;          // last prefetch harmless
        bf16x8 nw0 = *(const bf16x8*)(wpack + (size_t)((pn*2+0)*64 + lane)*8);
        bf16x8 nw1 = *(const bf16x8*)(wpack + (size_t)((pn*2+1)*64 + lane)*8);
        const __bf16* pa = pb + (ptrdiff_t)woff[p]*CIN;
        #pragma unroll
        for (int gi = 0; gi < 8; ++gi) {
            bf16x8 a = *(const bf16x8*)(pa + ((gi>>1)*WP + (gi&1)*16)*CIN);
            acc[gi][0] = __builtin_amdgcn_mfma_f32_16x16x32_bf16(a, w0, acc[gi][0], 0,0,0);
            acc[gi][1] = __builtin_amdgcn_mfma_f32_16x16x32_bf16(a, w1, acc[gi][1], 0,0,0);
        }
        w0 = nw0; w1 = nw1;
    }

    // writeback: D col = lane&15 = cout-in-half, row = (lane>>4)*4+reg = x-in-group
    #pragma unroll
    for (int gi = 0; gi < 8; ++gi) {
        int y = gi >> 1, xg = gi & 1;
        int gz = z0 + wave, gy = y0 + y, gx = x0 + xg*16 + ((lane >> 4) << 2);
        f32x4 o0, o1;
        o0[0] = fmaxf(acc[gi][0][0]+bv0, 0.f); o0[1] = fmaxf(acc[gi][0][1]+bv0, 0.f);
        o0[2] = fmaxf(acc[gi][0][2]+bv0, 0.f); o0[3] = fmaxf(acc[gi][0][3]+bv0, 0.f);
        o1[0] = fmaxf(acc[gi][1][0]+bv1, 0.f); o1[1] = fmaxf(acc[gi][1][1]+bv1, 0.f);
        o1[2] = fmaxf(acc[gi][1][2]+bv1, 0.f); o1[3] = fmaxf(acc[gi][1][3]+bv1, 0.f);
        size_t base0 = ((((size_t)b*COUT + lx16)*DSP + gz)*HSP + gy)*WSP + gx;
        size_t base1 = base0 + (size_t)16*DSP*HSP*WSP;
        __builtin_nontemporal_store(o0, (f32x4*)(out + base0));
        __builtin_nontemporal_store(o1, (f32x4*)(out + base1));
    }
}

extern "C" void kernel_launch(void* const* d_in, const int* in_sizes, int n_in,
                              void* d_out, int out_size, void* d_ws, size_t ws_size,
                              hipStream_t stream) {
    const float* feat   = (const float*)d_in[0];
    const int4*  coords = (const int4*)d_in[1];
    const float* weight = (const float*)d_in[2];
    const float* bias   = (const float*)d_in[3];
    float* out = (float*)d_out;
    int n = in_sizes[0] / CIN;

    // workspace: map 4MB | dense(padded) 36.8MB | wpack 28KB
    int*    map   = (int*)d_ws;
    __bf16* dense = (__bf16*)(map + NVOX);
    __bf16* wpack = dense + (size_t)NVOXP*CIN;

    hipMemsetAsync(map, 0xFF, (size_t)NVOX*sizeof(int), stream);
    hipMemsetAsync(dense, 0, (size_t)NVOXP*CIN*sizeof(__bf16), stream);

    int nb = (n + 255) / 256;
    k_prep   <<<nb + NWREP, 256, 0, stream>>>(coords, n, nb, map, weight, wpack);
    k_scatter<<<nb, 256, 0, stream>>>(coords, map, feat, dense, n);
    k_conv   <<<NTILES, 256, 0, stream>>>(dense, wpack, bias, out);
}

// Round 8
// 95.470 us; speedup vs baseline: 1.2447x; 1.2447x over previous
//
#include <hip/hip_runtime.h>

// Problem constants
#define CIN   16
#define COUT  32
#define BATCH 2
#define DSP   32
#define HSP   128
#define WSP   128
#define NVOX  (BATCH*DSP*HSP*WSP)   // 1,048,576 voxels (unpadded, dedup map)

// padded dense grid (1-voxel zero halo)
#define DP (DSP+2)     // 34
#define HP (HSP+2)     // 130
#define WP (WSP+2)     // 130
#define ZSTR (HP*WP)   // 16900
#define NVOXP (BATCH*DP*HP*WP)      // 1,149,200

// conv tile: 4(z) x 4(y) x 32(x); halo patch 6 x 6 x 34
#define TZ 4
#define TY 4
#define TX 32
#define NTILES 2048
#define PZ 6
#define PYY 6
#define PXX 34
#define PVOX (PZ*PYY*PXX)   // 1224 voxels
#define NCHUNK (2*PVOX)     // 2448 16B chunks ([half][voxel])
#define NPAIR 14            // 27 taps -> 14 K=32 pairs (last padded with zero weights)
#define NWREP ((NPAIR*2*64*8 + 255)/256)   // 56 repack blocks

typedef __bf16 bf16x8 __attribute__((ext_vector_type(8)));
typedef float  f32x4  __attribute__((ext_vector_type(4)));

// width-16 global->LDS DMA: uniform LDS base, per-lane global src
__device__ __forceinline__ void load_lds16(const void* g, void* l) {
    __builtin_amdgcn_global_load_lds(
        (const __attribute__((address_space(1))) unsigned*)g,
        (__attribute__((address_space(3))) unsigned*)l, 16, 0, 0);
}

// ---- fused: dedup (last-write-wins via atomicMax) + weight repack ----
// wpack flat idx = ((pair*2 + half)*64 + lane)*8 + j
// tap = 2*pair + ((lane>>4)>>1), ci = ((lane>>4)&1)*8 + j, cout = half*16 + (lane&15)
__global__ void k_prep(const int4* __restrict__ coords, int n, int nbDedup,
                       int* __restrict__ map,
                       const float* __restrict__ w, __bf16* __restrict__ wpack) {
    int bb = blockIdx.x;
    if (bb < nbDedup) {
        int p = bb * 256 + threadIdx.x;
        if (p >= n) return;
        int4 c = coords[p];
        int vox = ((c.x*DSP + c.y)*HSP + c.z)*WSP + c.w;
        atomicMax(&map[vox], p);
    } else {
        int i = (bb - nbDedup) * 256 + threadIdx.x;   // 14336 total
        if (i >= NPAIR*2*64*8) return;
        int j = i & 7, l = (i>>3) & 63, h = (i>>9) & 1, p = i >> 10;
        int tap = 2*p + ((l>>4)>>1);
        int co  = h*16 + (l & 15);
        int ci  = ((l>>4)&1)*8 + j;
        float v = (tap < 27) ? w[(co*CIN + ci)*27 + tap] : 0.0f;
        wpack[i] = (__bf16)v;
    }
}

// ---- winners write their bf16 feature vector into the PADDED dense grid ----
__global__ void k_scatter(const int4* __restrict__ coords, const int* __restrict__ map,
                          const float* __restrict__ feat, __bf16* __restrict__ dense,
                          int n) {
    int p = blockIdx.x * 256 + threadIdx.x;
    if (p >= n) return;
    int4 c = coords[p];
    int vox = ((c.x*DSP + c.y)*HSP + c.z)*WSP + c.w;
    if (map[vox] != p) return;                        // only last-writer survives
    const float4* fp = (const float4*)(feat + (size_t)p*CIN);
    float4 f0 = fp[0], f1 = fp[1], f2 = fp[2], f3 = fp[3];
    bf16x8 lo = { (__bf16)f0.x,(__bf16)f0.y,(__bf16)f0.z,(__bf16)f0.w,
                  (__bf16)f1.x,(__bf16)f1.y,(__bf16)f1.z,(__bf16)f1.w };
    bf16x8 hi = { (__bf16)f2.x,(__bf16)f2.y,(__bf16)f2.z,(__bf16)f2.w,
                  (__bf16)f3.x,(__bf16)f3.y,(__bf16)f3.z,(__bf16)f3.w };
    size_t voxp = (((size_t)c.x*DP + (c.y+1))*HP + (c.z+1))*WP + (c.w+1);
    __bf16* d = dense + voxp*CIN;
    *(bf16x8*)d       = lo;
    *(bf16x8*)(d + 8) = hi;
}

// ---- dense tiled conv (MFMA); patch staged via global_load_lds DMA ----
__global__ __launch_bounds__(256, 4) void k_conv(
    const __bf16* __restrict__ dense, const __bf16* __restrict__ wpack,
    const float* __restrict__ bias, float* __restrict__ out)
{
    __shared__ __align__(16) ushort patch[NCHUNK*8];  // 39168 B, [h][pz][py][px] x 16B

    // XCD-aware bijective swizzle: 2048 % 8 == 0
    int bid  = blockIdx.x;
    int tile = (bid & 7) * (NTILES/8) + (bid >> 3);
    int txi = tile & 3;
    int tyi = (tile >> 2) & 31;
    int tzi = (tile >> 7) & 7;
    int b   = tile >> 10;
    int z0 = tzi*TZ, y0 = tyi*TY, x0 = txi*TX;

    int tid  = threadIdx.x;
    int lane = tid & 63, wave = tid >> 6;

    // ---- stage patch: fire-and-forget DMA, uniform LDS base + per-lane src ----
    // chunk j: h = j/PVOX, v = j%PVOX; pz = v/(PYY*PXX), py = rem/PXX, px = rem%PXX
    // patch cell (padded grid): (z0+pz, y0+py, x0+px)  [+1 halo shift built into z0..]
    const __bf16* gbase = dense + ((((size_t)b*DP + z0)*HP + y0)*WP + x0)*CIN;
    for (int j0 = wave*64; j0 < NCHUNK; j0 += 256) {
        int j = j0 + lane;
        if (j < NCHUNK) {
            int h  = (j >= PVOX) ? 1 : 0;
            int v  = j - h*PVOX;
            int pz = v / (PYY*PXX);
            int rem = v - pz*(PYY*PXX);
            int py = rem / PXX;
            int px = rem - py*PXX;
            load_lds16(gbase + ((size_t)(pz*ZSTR + py*WP + px))*CIN + h*8,
                       (void*)(patch + (size_t)j0*8));   // uniform base per wave
        }
    }

    int lx16  = lane & 15;
    int lhalf = (lane >> 4) & 1;
    int ltp   = (lane >> 4) >> 1;

    // per-lane patch chunk offsets per tap-pair (16B units within a half)
    int voff[NPAIR];
    #pragma unroll
    for (int p = 0; p < NPAIR; ++p) {
        int tap = 2*p + ltp; if (tap > 26) tap = 26;   // A read in-bounds; B zero there
        int kd = tap/9, kh = (tap/3)%3, kw = tap%3;
        voff[p] = (kd*PYY + kh)*PXX + kw;
    }
    float bv0 = bias[lx16], bv1 = bias[16 + lx16];

    __syncthreads();   // drains vmcnt(0): all DMA chunks landed

    // ---- compute: pair-outer / group-inner, 1-deep weight prefetch ----
    // wave = z layer; gi -> y = gi>>1, xg = gi&1
    f32x4 acc[8][2];
    #pragma unroll
    for (int gi = 0; gi < 8; ++gi) {
        acc[gi][0] = (f32x4){0.f,0.f,0.f,0.f};
        acc[gi][1] = (f32x4){0.f,0.f,0.f,0.f};
    }
    const ushort* pb = patch + ((size_t)lhalf*PVOX + wave*(PYY*PXX) + lx16)*8;
    bf16x8 w0 = *(const bf16x8*)(wpack + (size_t)(0*64 + lane)*8);
    bf16x8 w1 = *(const bf16x8*)(wpack + (size_t)(1*64 + lane)*8);
    #pragma unroll
    for (int p = 0; p < NPAIR; ++p) {
        int pn = (p + 1 < NPAIR) ? p + 1 : 0;          // last prefetch harmless
        bf16x8 nw0 = *(const bf16x8*)(wpack + (size_t)((pn*2+0)*64 + lane)*8);
        bf16x8 nw1 = *(const bf16x8*)(wpack + (size_t)((pn*2+1)*64 + lane)*8);
        const ushort* pa = pb + (size_t)voff[p]*8;
        #pragma unroll
        for (int gi = 0; gi < 8; ++gi) {
            bf16x8 a = *(const bf16x8*)(pa + ((gi>>1)*PXX + (gi&1)*16)*8);
            acc[gi][0] = __builtin_amdgcn_mfma_f32_16x16x32_bf16(a, w0, acc[gi][0], 0,0,0);
            acc[gi][1] = __builtin_amdgcn_mfma_f32_16x16x32_bf16(a, w1, acc[gi][1], 0,0,0);
        }
        w0 = nw0; w1 = nw1;
    }

    // ---- writeback: full 128B lines per (cout,z,y) row (xg=0,1 adjacent) ----
    // D col = lane&15 = cout-in-half, row = (lane>>4)*4+reg = x-in-group
    #pragma unroll
    for (int gi = 0; gi < 8; ++gi) {
        int y = gi >> 1, xg = gi & 1;
        int gz = z0 + wave, gy = y0 + y, gx = x0 + xg*16 + ((lane >> 4) << 2);
        f32x4 o0, o1;
        o0[0] = fmaxf(acc[gi][0][0]+bv0, 0.f); o0[1] = fmaxf(acc[gi][0][1]+bv0, 0.f);
        o0[2] = fmaxf(acc[gi][0][2]+bv0, 0.f); o0[3] = fmaxf(acc[gi][0][3]+bv0, 0.f);
        o1[0] = fmaxf(acc[gi][1][0]+bv1, 0.f); o1[1] = fmaxf(acc[gi][1][1]+bv1, 0.f);
        o1[2] = fmaxf(acc[gi][1][2]+bv1, 0.f); o1[3] = fmaxf(acc[gi][1][3]+bv1, 0.f);
        size_t base0 = ((((size_t)b*COUT + lx16)*DSP + gz)*HSP + gy)*WSP + gx;
        size_t base1 = base0 + (size_t)16*DSP*HSP*WSP;
        __builtin_nontemporal_store(o0, (f32x4*)(out + base0));
        __builtin_nontemporal_store(o1, (f32x4*)(out + base1));
    }
}

extern "C" void kernel_launch(void* const* d_in, const int* in_sizes, int n_in,
                              void* d_out, int out_size, void* d_ws, size_t ws_size,
                              hipStream_t stream) {
    const float* feat   = (const float*)d_in[0];
    const int4*  coords = (const int4*)d_in[1];
    const float* weight = (const float*)d_in[2];
    const float* bias   = (const float*)d_in[3];
    float* out = (float*)d_out;
    int n = in_sizes[0] / CIN;

    // workspace: map 4MB | dense(padded) 36.8MB | wpack 28KB
    int*    map   = (int*)d_ws;
    __bf16* dense = (__bf16*)(map + NVOX);
    __bf16* wpack = dense + (size_t)NVOXP*CIN;

    hipMemsetAsync(map, 0xFF, (size_t)NVOX*sizeof(int), stream);
    hipMemsetAsync(dense, 0, (size_t)NVOXP*CIN*sizeof(__bf16), stream);

    int nb = (n + 255) / 256;
    k_prep   <<<nb + NWREP, 256, 0, stream>>>(coords, n, nb, map, weight, wpack);
    k_scatter<<<nb, 256, 0, stream>>>(coords, map, feat, dense, n);
    k_conv   <<<NTILES, 256, 0, stream>>>(dense, wpack, bias, out);
}

// Round 9
// 83.332 us; speedup vs baseline: 1.4261x; 1.1457x over previous
//
#include <hip/hip_runtime.h>

// Problem constants
#define CIN   16
#define COUT  32
#define BATCH 2
#define DSP   32
#define HSP   128
#define WSP   128
#define NVOX  (BATCH*DSP*HSP*WSP)   // 1,048,576 voxels (unpadded, dedup map)

// padded dense grid (1-voxel zero halo)
#define DP (DSP+2)     // 34
#define HP (HSP+2)     // 130
#define WP (WSP+2)     // 130
#define ZSTR (HP*WP)   // 16900
#define NVOXP (BATCH*DP*HP*WP)      // 1,149,200

// conv tile: 4(z) x 8(y) x 32(x); halo patch 6 x 10 x 34
#define TZ 4
#define TY 8
#define TX 32
#define NTZ 8               // DSP/TZ
#define NTY 16              // HSP/TY
#define NTX 4               // WSP/TX
#define NTILES 1024         // BATCH*NTZ*NTY*NTX
#define PZ 6
#define PYY 10
#define PXX 34
#define PVOX (PZ*PYY*PXX)   // 2040 voxels
#define NCHUNK (2*PVOX)     // 4080 16B chunks ([half][voxel])
#define NPAIR 14            // 27 taps -> 14 K=32 pairs (last padded with zero weights)
#define NWREP ((NPAIR*2*64*8 + 255)/256)   // 56 repack blocks

typedef __bf16 bf16x8 __attribute__((ext_vector_type(8)));
typedef float  f32x4  __attribute__((ext_vector_type(4)));

// width-16 global->LDS DMA: uniform LDS base, per-lane global src
__device__ __forceinline__ void load_lds16(const void* g, void* l) {
    __builtin_amdgcn_global_load_lds(
        (const __attribute__((address_space(1))) unsigned*)g,
        (__attribute__((address_space(3))) unsigned*)l, 16, 0, 0);
}

// ---- fused: dedup (last-write-wins via atomicMax) + weight repack ----
// wpack flat idx = ((pair*2 + half)*64 + lane)*8 + j
// tap = 2*pair + ((lane>>4)>>1), ci = ((lane>>4)&1)*8 + j, cout = half*16 + (lane&15)
__global__ void k_prep(const int4* __restrict__ coords, int n, int nbDedup,
                       int* __restrict__ map,
                       const float* __restrict__ w, __bf16* __restrict__ wpack) {
    int bb = blockIdx.x;
    if (bb < nbDedup) {
        int p = bb * 256 + threadIdx.x;
        if (p >= n) return;
        int4 c = coords[p];
        int vox = ((c.x*DSP + c.y)*HSP + c.z)*WSP + c.w;
        atomicMax(&map[vox], p);
    } else {
        int i = (bb - nbDedup) * 256 + threadIdx.x;   // 14336 total
        if (i >= NPAIR*2*64*8) return;
        int j = i & 7, l = (i>>3) & 63, h = (i>>9) & 1, p = i >> 10;
        int tap = 2*p + ((l>>4)>>1);
        int co  = h*16 + (l & 15);
        int ci  = ((l>>4)&1)*8 + j;
        float v = (tap < 27) ? w[(co*CIN + ci)*27 + tap] : 0.0f;
        wpack[i] = (__bf16)v;
    }
}

// ---- winners write their bf16 feature vector into the PADDED dense grid ----
__global__ void k_scatter(const int4* __restrict__ coords, const int* __restrict__ map,
                          const float* __restrict__ feat, __bf16* __restrict__ dense,
                          int n) {
    int p = blockIdx.x * 256 + threadIdx.x;
    if (p >= n) return;
    int4 c = coords[p];
    int vox = ((c.x*DSP + c.y)*HSP + c.z)*WSP + c.w;
    if (map[vox] != p) return;                        // only last-writer survives
    const float4* fp = (const float4*)(feat + (size_t)p*CIN);
    float4 f0 = fp[0], f1 = fp[1], f2 = fp[2], f3 = fp[3];
    bf16x8 lo = { (__bf16)f0.x,(__bf16)f0.y,(__bf16)f0.z,(__bf16)f0.w,
                  (__bf16)f1.x,(__bf16)f1.y,(__bf16)f1.z,(__bf16)f1.w };
    bf16x8 hi = { (__bf16)f2.x,(__bf16)f2.y,(__bf16)f2.z,(__bf16)f2.w,
                  (__bf16)f3.x,(__bf16)f3.y,(__bf16)f3.z,(__bf16)f3.w };
    size_t voxp = (((size_t)c.x*DP + (c.y+1))*HP + (c.z+1))*WP + (c.w+1);
    __bf16* d = dense + voxp*CIN;
    *(bf16x8*)d       = lo;
    *(bf16x8*)(d + 8) = hi;
}

// ---- dense tiled conv (MFMA); patch staged via global_load_lds DMA ----
// 512 threads = 8 waves; wave w: z = w>>1, y-half = (w&1)*4
__global__ __launch_bounds__(512, 4) void k_conv(
    const __bf16* __restrict__ dense, const __bf16* __restrict__ wpack,
    const float* __restrict__ bias, float* __restrict__ out)
{
    __shared__ __align__(16) ushort patch[NCHUNK*8];  // 65280 B, [h][pz][py][px] x 16B

    // XCD-aware bijective swizzle: 1024 % 8 == 0
    int bid  = blockIdx.x;
    int tile = (bid & 7) * (NTILES/8) + (bid >> 3);
    int txi = tile & 3;
    int tyi = (tile >> 2) & 15;
    int tzi = (tile >> 6) & 7;
    int b   = tile >> 9;
    int z0 = tzi*TZ, y0 = tyi*TY, x0 = txi*TX;

    int tid  = threadIdx.x;
    int lane = tid & 63, wave = tid >> 6;

    // ---- stage patch: fire-and-forget DMA, uniform LDS base + per-lane src ----
    // chunk j: h = j/PVOX, v = j%PVOX; pz = v/(PYY*PXX), py = rem/PXX, px = rem%PXX
    const __bf16* gbase = dense + ((((size_t)b*DP + z0)*HP + y0)*WP + x0)*CIN;
    for (int j0 = wave*64; j0 < NCHUNK; j0 += 512) {
        int j = j0 + lane;
        if (j < NCHUNK) {
            int h  = (j >= PVOX) ? 1 : 0;
            int v  = j - h*PVOX;
            int pz = v / (PYY*PXX);
            int rem = v - pz*(PYY*PXX);
            int py = rem / PXX;
            int px = rem - py*PXX;
            load_lds16(gbase + ((size_t)(pz*ZSTR + py*WP + px))*CIN + h*8,
                       (void*)(patch + (size_t)j0*8));   // uniform base per wave
        }
    }

    int lx16  = lane & 15;
    int lhalf = (lane >> 4) & 1;
    int ltp   = (lane >> 4) >> 1;
    int zw    = wave >> 1;
    int yb    = (wave & 1) * 4;

    // per-lane patch voxel offsets per tap-pair (16B units within a half)
    int voff[NPAIR];
    #pragma unroll
    for (int p = 0; p < NPAIR; ++p) {
        int tap = 2*p + ltp; if (tap > 26) tap = 26;   // A read in-bounds; B zero there
        int kd = tap/9, kh = (tap/3)%3, kw = tap%3;
        voff[p] = (kd*PYY + kh)*PXX + kw;
    }
    float bv0 = bias[lx16], bv1 = bias[16 + lx16];

    __syncthreads();   // drains vmcnt(0): all DMA chunks landed

    // ---- compute: pair-outer / group-inner, 1-deep weight prefetch ----
    // gi -> y = gi>>1 (4 rows), xg = gi&1 (two 16x groups)
    f32x4 acc[8][2];
    #pragma unroll
    for (int gi = 0; gi < 8; ++gi) {
        acc[gi][0] = (f32x4){0.f,0.f,0.f,0.f};
        acc[gi][1] = (f32x4){0.f,0.f,0.f,0.f};
    }
    const ushort* pb = patch + ((size_t)lhalf*PVOX + (zw*PYY + yb)*PXX + lx16)*8;
    bf16x8 w0 = *(const bf16x8*)(wpack + (size_t)(0*64 + lane)*8);
    bf16x8 w1 = *(const bf16x8*)(wpack + (size_t)(1*64 + lane)*8);
    #pragma unroll
    for (int p = 0; p < NPAIR; ++p) {
        int pn = (p + 1 < NPAIR) ? p + 1 : 0;          // last prefetch harmless
        bf16x8 nw0 = *(const bf16x8*)(wpack + (size_t)((pn*2+0)*64 + lane)*8);
        bf16x8 nw1 = *(const bf16x8*)(wpack + (size_t)((pn*2+1)*64 + lane)*8);
        const ushort* pa = pb + (size_t)voff[p]*8;
        #pragma unroll
        for (int gi = 0; gi < 8; ++gi) {
            bf16x8 a = *(const bf16x8*)(pa + ((gi>>1)*PXX + (gi&1)*16)*8);
            acc[gi][0] = __builtin_amdgcn_mfma_f32_16x16x32_bf16(a, w0, acc[gi][0], 0,0,0);
            acc[gi][1] = __builtin_amdgcn_mfma_f32_16x16x32_bf16(a, w1, acc[gi][1], 0,0,0);
        }
        w0 = nw0; w1 = nw1;
    }

    // ---- writeback: plain cached stores; full 128B lines per (cout,z,y) row ----
    // D col = lane&15 = cout-in-half, row = (lane>>4)*4+reg = x-in-group
    #pragma unroll
    for (int gi = 0; gi < 8; ++gi) {
        int y = yb + (gi >> 1), xg = gi & 1;
        int gz = z0 + zw, gy = y0 + y, gx = x0 + xg*16 + ((lane >> 4) << 2);
        f32x4 o0, o1;
        o0[0] = fmaxf(acc[gi][0][0]+bv0, 0.f); o0[1] = fmaxf(acc[gi][0][1]+bv0, 0.f);
        o0[2] = fmaxf(acc[gi][0][2]+bv0, 0.f); o0[3] = fmaxf(acc[gi][0][3]+bv0, 0.f);
        o1[0] = fmaxf(acc[gi][1][0]+bv1, 0.f); o1[1] = fmaxf(acc[gi][1][1]+bv1, 0.f);
        o1[2] = fmaxf(acc[gi][1][2]+bv1, 0.f); o1[3] = fmaxf(acc[gi][1][3]+bv1, 0.f);
        size_t base0 = ((((size_t)b*COUT + lx16)*DSP + gz)*HSP + gy)*WSP + gx;
        size_t base1 = base0 + (size_t)16*DSP*HSP*WSP;
        *(f32x4*)(out + base0) = o0;
        *(f32x4*)(out + base1) = o1;
    }
}

extern "C" void kernel_launch(void* const* d_in, const int* in_sizes, int n_in,
                              void* d_out, int out_size, void* d_ws, size_t ws_size,
                              hipStream_t stream) {
    const float* feat   = (const float*)d_in[0];
    const int4*  coords = (const int4*)d_in[1];
    const float* weight = (const float*)d_in[2];
    const float* bias   = (const float*)d_in[3];
    float* out = (float*)d_out;
    int n = in_sizes[0] / CIN;

    // workspace: map 4MB | dense(padded) 36.8MB | wpack 28KB
    int*    map   = (int*)d_ws;
    __bf16* dense = (__bf16*)(map + NVOX);
    __bf16* wpack = dense + (size_t)NVOXP*CIN;

    hipMemsetAsync(map, 0xFF, (size_t)NVOX*sizeof(int), stream);
    hipMemsetAsync(dense, 0, (size_t)NVOXP*CIN*sizeof(__bf16), stream);

    int nb = (n + 255) / 256;
    k_prep   <<<nb + NWREP, 256, 0, stream>>>(coords, n, nb, map, weight, wpack);
    k_scatter<<<nb, 256, 0, stream>>>(coords, map, feat, dense, n);
    k_conv   <<<NTILES, 512, 0, stream>>>(dense, wpack, bias, out);
}

// Round 10
// 82.664 us; speedup vs baseline: 1.4376x; 1.0081x over previous
//
#include <hip/hip_runtime.h>

// Problem constants
#define CIN   16
#define COUT  32
#define BATCH 2
#define DSP   32
#define HSP   128
#define WSP   128
#define NVOX  (BATCH*DSP*HSP*WSP)   // 1,048,576 voxels (unpadded, dedup map)

// padded dense grid (1-voxel zero halo)
#define DP (DSP+2)     // 34
#define HP (HSP+2)     // 130
#define WP (WSP+2)     // 130
#define ZSTR (HP*WP)   // 16900
#define NVOXP (BATCH*DP*HP*WP)      // 1,149,200

// conv tile: 4(z) x 8(y) x 32(x); halo patch 6 x 10 x 34
#define TZ 4
#define TY 8
#define TX 32
#define PZ 6
#define PYY 10
#define PXX 34
#define PROW (PYY*PXX)      // 340
#define PVOX (PZ*PROW)      // 2040 voxels
#define NCHUNK (2*PVOX)     // 4080 16B chunks ([half][voxel])
#define NCHPAD 4096         // padded to 8 waves * 8 issues * 64 lanes
#define NPAIR 14            // 27 taps -> 14 K=32 pairs (last padded with zero weights)
#define NWREP ((NPAIR*2*64*8 + 255)/256)          // 56 repack blocks
#define FILLT (NVOXP*CIN/8)                        // uint4 chunks of dense (2,298,400)
#define NFILL ((FILLT + 255)/256)                  // 8979 fill blocks

typedef __bf16 bf16x8 __attribute__((ext_vector_type(8)));
typedef float  f32x4  __attribute__((ext_vector_type(4)));

// width-16 global->LDS DMA: uniform LDS base, per-lane global src
__device__ __forceinline__ void load_lds16(const void* g, void* l) {
    __builtin_amdgcn_global_load_lds(
        (const __attribute__((address_space(1))) unsigned*)g,
        (__attribute__((address_space(3))) unsigned*)l, 16, 0, 0);
}

// ---- fused: dedup (atomicMax last-write-wins) + weight repack + dense zero ----
__global__ void k_prep(const int4* __restrict__ coords, int n, int nbDedup,
                       int* __restrict__ map,
                       const float* __restrict__ w, __bf16* __restrict__ wpack,
                       uint4* __restrict__ dense4) {
    int bb = blockIdx.x;
    if (bb < nbDedup) {
        int p = bb * 256 + threadIdx.x;
        if (p >= n) return;
        int4 c = coords[p];
        int vox = ((c.x*DSP + c.y)*HSP + c.z)*WSP + c.w;
        atomicMax(&map[vox], p);
    } else if (bb < nbDedup + NWREP) {
        // wpack flat idx = ((pair*2 + half)*64 + lane)*8 + j
        // tap = 2*pair + ((lane>>4)>>1), ci = ((lane>>4)&1)*8 + j, cout = half*16+(lane&15)
        int i = (bb - nbDedup) * 256 + threadIdx.x;   // 14336 total
        if (i >= NPAIR*2*64*8) return;
        int j = i & 7, l = (i>>3) & 63, h = (i>>9) & 1, p = i >> 10;
        int tap = 2*p + ((l>>4)>>1);
        int co  = h*16 + (l & 15);
        int ci  = ((l>>4)&1)*8 + j;
        float v = (tap < 27) ? w[(co*CIN + ci)*27 + tap] : 0.0f;
        wpack[i] = (__bf16)v;
    } else {
        int i = (bb - nbDedup - NWREP) * 256 + threadIdx.x;
        if (i < FILLT) dense4[i] = make_uint4(0,0,0,0);
    }
}

// ---- winners write their bf16 feature vector into the PADDED dense grid ----
__global__ void k_scatter(const int4* __restrict__ coords, const int* __restrict__ map,
                          const float* __restrict__ feat, __bf16* __restrict__ dense,
                          int n) {
    int p = blockIdx.x * 256 + threadIdx.x;
    if (p >= n) return;
    int4 c = coords[p];
    int vox = ((c.x*DSP + c.y)*HSP + c.z)*WSP + c.w;
    if (map[vox] != p) return;                        // only last-writer survives
    const float4* fp = (const float4*)(feat + (size_t)p*CIN);
    float4 f0 = fp[0], f1 = fp[1], f2 = fp[2], f3 = fp[3];
    bf16x8 lo = { (__bf16)f0.x,(__bf16)f0.y,(__bf16)f0.z,(__bf16)f0.w,
                  (__bf16)f1.x,(__bf16)f1.y,(__bf16)f1.z,(__bf16)f1.w };
    bf16x8 hi = { (__bf16)f2.x,(__bf16)f2.y,(__bf16)f2.z,(__bf16)f2.w,
                  (__bf16)f3.x,(__bf16)f3.y,(__bf16)f3.z,(__bf16)f3.w };
    size_t voxp = (((size_t)c.x*DP + (c.y+1))*HP + (c.z+1))*WP + (c.w+1);
    __bf16* d = dense + voxp*CIN;
    *(bf16x8*)d       = lo;
    *(bf16x8*)(d + 8) = hi;
}

// issue exactly 8 DMA per wave for one tile's patch (uniform vmcnt accounting)
__device__ __forceinline__ void stage_tile(const __bf16* __restrict__ gb,
                                           ushort* lbase, int wave, int lane) {
    #pragma unroll
    for (int it = 0; it < 8; ++it) {
        int j0 = wave*64 + it*512;                    // wave-uniform LDS chunk base
        int j  = j0 + lane;
        int jj = j < NCHUNK ? j : NCHUNK-1;           // clamp pad lanes (dup load)
        int h  = (jj >= PVOX) ? 1 : 0;
        int v  = jj - h*PVOX;
        int pz = v / PROW;
        int rem = v - pz*PROW;
        int py = rem / PXX;
        int px = rem - py*PXX;
        load_lds16(gb + ((size_t)(pz*ZSTR + py*WP + px))*CIN + h*8,
                   (void*)(lbase + (size_t)j0*8));
    }
}

// ---- persistent pipelined dense conv (MFMA): 1 block/CU, 4 tiles, 2-deep dbuf ----
__global__ __launch_bounds__(512, 2) void k_conv(
    const __bf16* __restrict__ dense, const __bf16* __restrict__ wpack,
    const float* __restrict__ bias, float* __restrict__ out)
{
    __shared__ __align__(16) ushort patch[2][NCHPAD*8];   // 2 x 64 KiB

    // 256 blocks <-> (b, tz, ty); XCD-aware bijective swizzle (256 % 8 == 0)
    int bid = blockIdx.x;
    int bs  = (bid & 7) * 32 + (bid >> 3);
    int tyi = bs & 15, tzi = (bs >> 4) & 7, b = bs >> 7;
    int z0 = tzi*TZ, y0 = tyi*TY;

    int tid  = threadIdx.x;
    int lane = tid & 63, wave = tid >> 6;
    int lx16  = lane & 15;
    int lhalf = (lane >> 4) & 1;
    int ltp   = (lane >> 4) >> 1;
    int zw    = wave >> 1;
    int yb    = (wave & 1) * 4;

    // per-lane patch voxel offsets per tap-pair (16B units within a half)
    int voff[NPAIR];
    #pragma unroll
    for (int p = 0; p < NPAIR; ++p) {
        int tap = 2*p + ltp; if (tap > 26) tap = 26;   // A read in-bounds; B zero there
        int kd = tap/9, kh = (tap/3)%3, kw = tap%3;
        voff[p] = (kd*PYY + kh)*PXX + kw;
    }
    float bv0 = bias[lx16], bv1 = bias[16 + lx16];

    // preload ALL weight fragments into registers once (28 dwordx4 = 112 VGPR)
    bf16x8 wf[NPAIR][2];
    #pragma unroll
    for (int p = 0; p < NPAIR; ++p)
        #pragma unroll
        for (int h = 0; h < 2; ++h)
            wf[p][h] = *(const bf16x8*)(wpack + (size_t)((p*2 + h)*64 + lane)*8);

    const __bf16* grow = dense + ((((size_t)b*DP + z0)*HP + y0)*WP)*CIN;

    // prologue: stage tile 0
    stage_tile(grow, patch[0], wave, lane);

    #pragma unroll 1
    for (int t = 0; t < 4; ++t) {
        // issue next tile's stage (fire-and-forget), then wait for CURRENT tile only
        if (t < 3) {
            stage_tile(grow + (size_t)(t+1)*TX*CIN, patch[(t+1)&1], wave, lane);
            asm volatile("s_waitcnt vmcnt(8)\ns_barrier" ::: "memory");
        } else {
            asm volatile("s_waitcnt vmcnt(0)\ns_barrier" ::: "memory");
        }
        __builtin_amdgcn_sched_barrier(0);

        // ---- compute tile t from patch[t&1]; zero global loads in this phase ----
        f32x4 acc[8][2];
        #pragma unroll
        for (int gi = 0; gi < 8; ++gi) {
            acc[gi][0] = (f32x4){0.f,0.f,0.f,0.f};
            acc[gi][1] = (f32x4){0.f,0.f,0.f,0.f};
        }
        const ushort* pb = patch[t&1] +
            ((size_t)lhalf*PVOX + (zw*PYY + yb)*PXX + lx16)*8;
        #pragma unroll
        for (int p = 0; p < NPAIR; ++p) {
            const ushort* pa = pb + (size_t)voff[p]*8;
            #pragma unroll
            for (int gi = 0; gi < 8; ++gi) {
                bf16x8 a = *(const bf16x8*)(pa + ((gi>>1)*PXX + (gi&1)*16)*8);
                acc[gi][0] = __builtin_amdgcn_mfma_f32_16x16x32_bf16(a, wf[p][0], acc[gi][0], 0,0,0);
                acc[gi][1] = __builtin_amdgcn_mfma_f32_16x16x32_bf16(a, wf[p][1], acc[gi][1], 0,0,0);
            }
        }

        // all waves done reading patch[t&1] -> next iteration may overwrite it
        asm volatile("s_barrier" ::: "memory");
        __builtin_amdgcn_sched_barrier(0);

        // ---- writeback tile t: full 128B lines, plain cached stores ----
        #pragma unroll
        for (int gi = 0; gi < 8; ++gi) {
            int y = yb + (gi >> 1), xg = gi & 1;
            int gz = z0 + zw, gy = y0 + y;
            int gx = t*TX + xg*16 + ((lane >> 4) << 2);
            f32x4 o0, o1;
            o0[0] = fmaxf(acc[gi][0][0]+bv0, 0.f); o0[1] = fmaxf(acc[gi][0][1]+bv0, 0.f);
            o0[2] = fmaxf(acc[gi][0][2]+bv0, 0.f); o0[3] = fmaxf(acc[gi][0][3]+bv0, 0.f);
            o1[0] = fmaxf(acc[gi][1][0]+bv1, 0.f); o1[1] = fmaxf(acc[gi][1][1]+bv1, 0.f);
            o1[2] = fmaxf(acc[gi][1][2]+bv1, 0.f); o1[3] = fmaxf(acc[gi][1][3]+bv1, 0.f);
            size_t base0 = ((((size_t)b*COUT + lx16)*DSP + gz)*HSP + gy)*WSP + gx;
            size_t base1 = base0 + (size_t)16*DSP*HSP*WSP;
            *(f32x4*)(out + base0) = o0;
            *(f32x4*)(out + base1) = o1;
        }
    }
}

extern "C" void kernel_launch(void* const* d_in, const int* in_sizes, int n_in,
                              void* d_out, int out_size, void* d_ws, size_t ws_size,
                              hipStream_t stream) {
    const float* feat   = (const float*)d_in[0];
    const int4*  coords = (const int4*)d_in[1];
    const float* weight = (const float*)d_in[2];
    const float* bias   = (const float*)d_in[3];
    float* out = (float*)d_out;
    int n = in_sizes[0] / CIN;

    // workspace: map 4MB | dense(padded) 36.8MB | wpack 28KB
    int*    map   = (int*)d_ws;
    __bf16* dense = (__bf16*)(map + NVOX);
    __bf16* wpack = dense + (size_t)NVOXP*CIN;

    hipMemsetAsync(map, 0xFF, (size_t)NVOX*sizeof(int), stream);

    int nb = (n + 255) / 256;
    k_prep   <<<nb + NWREP + NFILL, 256, 0, stream>>>(coords, n, nb, map, weight,
                                                      wpack, (uint4*)dense);
    k_scatter<<<nb, 256, 0, stream>>>(coords, map, feat, dense, n);
    k_conv   <<<256, 512, 0, stream>>>(dense, wpack, bias, out);
}

// Round 11
// 73.410 us; speedup vs baseline: 1.6188x; 1.1261x over previous
//
#include <hip/hip_runtime.h>

// Problem constants
#define CIN   16
#define COUT  32
#define BATCH 2
#define DSP   32
#define HSP   128
#define WSP   128
#define NVOX  (BATCH*DSP*HSP*WSP)   // 1,048,576 voxels (unpadded, dedup map)

// padded dense grid (1-voxel zero halo)
#define DP (DSP+2)     // 34
#define HP (HSP+2)     // 130
#define WP (WSP+2)     // 130
#define ZSTR (HP*WP)   // 16900
#define NVOXP (BATCH*DP*HP*WP)      // 1,149,200
#define NDCH  (NVOXP*2)             // 16B chunks of dense (2,298,400)

// conv tile: 4(z) x 8(y) x 32(x); halo patch 6 x 10 x 34
#define TZ 4
#define TY 8
#define TX 32
#define PZ 6
#define PYY 10
#define PXX 34
#define PROW (PYY*PXX)      // 340
#define PVOX (PZ*PROW)      // 2040 voxels
#define NCHUNK (2*PVOX)     // 4080 16B chunks ([half][voxel])
#define NCHPAD 4096         // padded to 8 waves * 8 issues * 64 lanes
#define NPAIR 14            // 27 taps -> 14 K=32 pairs (last padded with zero weights)
#define NWREP ((NPAIR*2*64*8 + 255)/256)          // 56 repack blocks

typedef __bf16 bf16x8 __attribute__((ext_vector_type(8)));
typedef float  f32x4  __attribute__((ext_vector_type(4)));

// width-16 global->LDS DMA: uniform LDS base, per-lane global src
__device__ __forceinline__ void load_lds16(const void* g, void* l) {
    __builtin_amdgcn_global_load_lds(
        (const __attribute__((address_space(1))) unsigned*)g,
        (__attribute__((address_space(3))) unsigned*)l, 16, 0, 0);
}

// ---- fused: dedup (atomicMax last-write-wins) + weight repack ----
__global__ void k_prep(const int4* __restrict__ coords, int n, int nbDedup,
                       int* __restrict__ map,
                       const float* __restrict__ w, __bf16* __restrict__ wpack) {
    int bb = blockIdx.x;
    if (bb < nbDedup) {
        int p = bb * 256 + threadIdx.x;
        if (p >= n) return;
        int4 c = coords[p];
        int vox = ((c.x*DSP + c.y)*HSP + c.z)*WSP + c.w;
        atomicMax(&map[vox], p);
    } else {
        // wpack flat idx = ((pair*2 + half)*64 + lane)*8 + j
        // tap = 2*pair + ((lane>>4)>>1), ci = ((lane>>4)&1)*8 + j, cout = half*16+(lane&15)
        int i = (bb - nbDedup) * 256 + threadIdx.x;   // 14336 total
        if (i >= NPAIR*2*64*8) return;
        int j = i & 7, l = (i>>3) & 63, h = (i>>9) & 1, p = i >> 10;
        int tap = 2*p + ((l>>4)>>1);
        int co  = h*16 + (l & 15);
        int ci  = ((l>>4)&1)*8 + j;
        float v = (tap < 27) ? w[(co*CIN + ci)*27 + tap] : 0.0f;
        wpack[i] = (__bf16)v;
    }
}

// ---- dense fill: one thread per 16B chunk; zeros or gathered bf16 features ----
// Replaces separate zero-fill + scattered writes: fully coalesced 36.8 MB write.
__global__ void k_fill(const int* __restrict__ map, const float* __restrict__ feat,
                       __bf16* __restrict__ dense) {
    int c = blockIdx.x * 256 + threadIdx.x;
    if (c >= NDCH) return;
    int v = c >> 1, h = c & 1;
    int bb = v / (DP*ZSTR);
    int r  = v - bb*(DP*ZSTR);
    int zp = r / ZSTR;  r -= zp*ZSTR;
    int yp = r / WP;
    int xp = r - yp*WP;
    bf16x8 val = { (__bf16)0.f,(__bf16)0.f,(__bf16)0.f,(__bf16)0.f,
                   (__bf16)0.f,(__bf16)0.f,(__bf16)0.f,(__bf16)0.f };
    if ((unsigned)(zp-1) < DSP && (unsigned)(yp-1) < HSP && (unsigned)(xp-1) < WSP) {
        int vox = ((bb*DSP + (zp-1))*HSP + (yp-1))*WSP + (xp-1);
        int p = map[vox];
        if (p >= 0) {
            const float4* fp = (const float4*)(feat + (size_t)p*CIN) + h*2;
            float4 f0 = fp[0], f1 = fp[1];
            val = bf16x8{ (__bf16)f0.x,(__bf16)f0.y,(__bf16)f0.z,(__bf16)f0.w,
                          (__bf16)f1.x,(__bf16)f1.y,(__bf16)f1.z,(__bf16)f1.w };
        }
    }
    *(bf16x8*)(dense + (size_t)v*CIN + h*8) = val;
}

// issue exactly 8 DMA per wave for one tile's patch (uniform vmcnt accounting)
__device__ __forceinline__ void stage_tile(const __bf16* __restrict__ gb,
                                           ushort* lbase, int wave, int lane) {
    #pragma unroll
    for (int it = 0; it < 8; ++it) {
        int j0 = wave*64 + it*512;                    // wave-uniform LDS chunk base
        int j  = j0 + lane;
        int jj = j < NCHUNK ? j : NCHUNK-1;           // clamp pad lanes (dup load)
        int h  = (jj >= PVOX) ? 1 : 0;
        int v  = jj - h*PVOX;
        int pz = v / PROW;
        int rem = v - pz*PROW;
        int py = rem / PXX;
        int px = rem - py*PXX;
        load_lds16(gb + ((size_t)(pz*ZSTR + py*WP + px))*CIN + h*8,
                   (void*)(lbase + (size_t)j0*8));
    }
}

// ---- persistent pipelined dense conv (MFMA): 1 block/CU, 4 tiles, 2-deep dbuf ----
// vmcnt discipline (stores count in the same FIFO, oldest-first retirement):
//   queue at iter-t wait: [stage(t):8][wb(t-1):16][stage(t+1):8]
//   t=0: vmcnt(8)  (no stores yet) | t=1,2: vmcnt(24) | t=3: vmcnt(16) (no stage(4))
__global__ __launch_bounds__(512, 2) void k_conv(
    const __bf16* __restrict__ dense, const __bf16* __restrict__ wpack,
    const float* __restrict__ bias, float* __restrict__ out)
{
    __shared__ __align__(16) ushort patch[2][NCHPAD*8];   // 2 x 64 KiB

    // 256 blocks <-> (b, tz, ty); XCD-aware bijective swizzle (256 % 8 == 0)
    int bid = blockIdx.x;
    int bs  = (bid & 7) * 32 + (bid >> 3);
    int tyi = bs & 15, tzi = (bs >> 4) & 7, b = bs >> 7;
    int z0 = tzi*TZ, y0 = tyi*TY;

    int tid  = threadIdx.x;
    int lane = tid & 63, wave = tid >> 6;
    int lx16  = lane & 15;
    int lhalf = (lane >> 4) & 1;
    int ltp   = (lane >> 4) >> 1;
    int zw    = wave >> 1;
    int yb    = (wave & 1) * 4;

    // per-lane patch voxel offsets per tap-pair (16B units within a half)
    int voff[NPAIR];
    #pragma unroll
    for (int p = 0; p < NPAIR; ++p) {
        int tap = 2*p + ltp; if (tap > 26) tap = 26;   // A read in-bounds; B zero there
        int kd = tap/9, kh = (tap/3)%3, kw = tap%3;
        voff[p] = (kd*PYY + kh)*PXX + kw;
    }
    float bv0 = bias[lx16], bv1 = bias[16 + lx16];

    // preload ALL weight fragments into registers once (28 dwordx4 = 112 VGPR)
    bf16x8 wf[NPAIR][2];
    #pragma unroll
    for (int p = 0; p < NPAIR; ++p)
        #pragma unroll
        for (int h = 0; h < 2; ++h)
            wf[p][h] = *(const bf16x8*)(wpack + (size_t)((p*2 + h)*64 + lane)*8);

    const __bf16* grow = dense + ((((size_t)b*DP + z0)*HP + y0)*WP)*CIN;

    // prologue: stage tile 0
    stage_tile(grow, patch[0], wave, lane);

    #pragma unroll 1
    for (int t = 0; t < 4; ++t) {
        // issue next tile's stage (fire-and-forget), then wait for CURRENT tile only
        if (t < 3) stage_tile(grow + (size_t)(t+1)*TX*CIN, patch[(t+1)&1], wave, lane);
        if (t == 0)      asm volatile("s_waitcnt vmcnt(8)\ns_barrier"  ::: "memory");
        else if (t < 3)  asm volatile("s_waitcnt vmcnt(24)\ns_barrier" ::: "memory");
        else             asm volatile("s_waitcnt vmcnt(16)\ns_barrier" ::: "memory");
        __builtin_amdgcn_sched_barrier(0);

        // ---- compute tile t from patch[t&1]; zero global loads in this phase ----
        f32x4 acc[8][2];
        #pragma unroll
        for (int gi = 0; gi < 8; ++gi) {
            acc[gi][0] = (f32x4){0.f,0.f,0.f,0.f};
            acc[gi][1] = (f32x4){0.f,0.f,0.f,0.f};
        }
        const ushort* pb = patch[t&1] +
            ((size_t)lhalf*PVOX + (zw*PYY + yb)*PXX + lx16)*8;
        #pragma unroll
        for (int p = 0; p < NPAIR; ++p) {
            const ushort* pa = pb + (size_t)voff[p]*8;
            #pragma unroll
            for (int gi = 0; gi < 8; ++gi) {
                bf16x8 a = *(const bf16x8*)(pa + ((gi>>1)*PXX + (gi&1)*16)*8);
                acc[gi][0] = __builtin_amdgcn_mfma_f32_16x16x32_bf16(a, wf[p][0], acc[gi][0], 0,0,0);
                acc[gi][1] = __builtin_amdgcn_mfma_f32_16x16x32_bf16(a, wf[p][1], acc[gi][1], 0,0,0);
            }
        }

        // all waves done reading patch[t&1] -> stage(t+2) may overwrite it next iter
        asm volatile("s_barrier" ::: "memory");
        __builtin_amdgcn_sched_barrier(0);

        // ---- writeback tile t: full 128B lines, plain cached stores ----
        #pragma unroll
        for (int gi = 0; gi < 8; ++gi) {
            int y = yb + (gi >> 1), xg = gi & 1;
            int gz = z0 + zw, gy = y0 + y;
            int gx = t*TX + xg*16 + ((lane >> 4) << 2);
            f32x4 o0, o1;
            o0[0] = fmaxf(acc[gi][0][0]+bv0, 0.f); o0[1] = fmaxf(acc[gi][0][1]+bv0, 0.f);
            o0[2] = fmaxf(acc[gi][0][2]+bv0, 0.f); o0[3] = fmaxf(acc[gi][0][3]+bv0, 0.f);
            o1[0] = fmaxf(acc[gi][1][0]+bv1, 0.f); o1[1] = fmaxf(acc[gi][1][1]+bv1, 0.f);
            o1[2] = fmaxf(acc[gi][1][2]+bv1, 0.f); o1[3] = fmaxf(acc[gi][1][3]+bv1, 0.f);
            size_t base0 = ((((size_t)b*COUT + lx16)*DSP + gz)*HSP + gy)*WSP + gx;
            size_t base1 = base0 + (size_t)16*DSP*HSP*WSP;
            *(f32x4*)(out + base0) = o0;
            *(f32x4*)(out + base1) = o1;
        }
    }
}

extern "C" void kernel_launch(void* const* d_in, const int* in_sizes, int n_in,
                              void* d_out, int out_size, void* d_ws, size_t ws_size,
                              hipStream_t stream) {
    const float* feat   = (const float*)d_in[0];
    const int4*  coords = (const int4*)d_in[1];
    const float* weight = (const float*)d_in[2];
    const float* bias   = (const float*)d_in[3];
    float* out = (float*)d_out;
    int n = in_sizes[0] / CIN;

    // workspace: map 4MB | dense(padded) 36.8MB | wpack 28KB
    int*    map   = (int*)d_ws;
    __bf16* dense = (__bf16*)(map + NVOX);
    __bf16* wpack = dense + (size_t)NVOXP*CIN;

    hipMemsetAsync(map, 0xFF, (size_t)NVOX*sizeof(int), stream);

    int nb = (n + 255) / 256;
    k_prep<<<nb + NWREP, 256, 0, stream>>>(coords, n, nb, map, weight, wpack);
    k_fill<<<(NDCH + 255)/256, 256, 0, stream>>>(map, feat, dense);
    k_conv<<<256, 512, 0, stream>>>(dense, wpack, bias, out);
}